// Round 1
// baseline (852.658 us; speedup 1.0000x reference)
//
#include <hip/hip_runtime.h>

#define N_NODES 20000
#define N_EDGES 320000
#define FF 64
#define KK 32

// ws layout (floats):
//   xA   : N_NODES*4*64 = 5,120,000
//   xB   : 5,120,000
//   geom : N_EDGES*4    = 1,280,000  (d, rhx, rhy, rhz)
// total 11,520,000 floats = 46.08 MB

__global__ __launch_bounds__(256) void edge_geom_k(const float* __restrict__ coords,
                                                   const int* __restrict__ dst,
                                                   const int* __restrict__ src,
                                                   float4* __restrict__ geom) {
    int e = blockIdx.x * 256 + threadIdx.x;
    if (e >= N_EDGES) return;
    int di = dst[e], si = src[e];
    float rx = coords[di*3+0] - coords[si*3+0];
    float ry = coords[di*3+1] - coords[si*3+1];
    float rz = coords[di*3+2] - coords[si*3+2];
    float d = sqrtf(rx*rx + ry*ry + rz*rz + 1e-12f);
    float inv = 1.0f / d;
    geom[e] = make_float4(d, rx*inv, ry*inv, rz*inv);
}

#define NPB 8
__global__ __launch_bounds__(256) void node_in_k(const float* __restrict__ x_dftb,
                                                 const float* __restrict__ W0,
                                                 const float* __restrict__ W1,
                                                 const float* __restrict__ bin,
                                                 float* __restrict__ x) {
    __shared__ float Wl[2*64*64];   // 32 KB
    __shared__ float xin[NPB*256];  // 8 KB
    int t = threadIdx.x;
    #pragma unroll
    for (int i = t; i < 8192; i += 256) Wl[i] = (i < 4096) ? W0[i] : W1[i-4096];
    int base = blockIdx.x * NPB;
    #pragma unroll
    for (int i = t; i < NPB*256; i += 256) xin[i] = x_dftb[base*256 + i];
    __syncthreads();
    int l = t >> 6, f = t & 63;
    const float* W = (l == 0) ? Wl : (Wl + 4096);
    float bb = (l == 0) ? bin[f] : 0.0f;
    for (int nn = 0; nn < NPB; ++nn) {
        float acc = bb;
        #pragma unroll
        for (int k = 0; k < 64; ++k) acc += xin[nn*256 + l*64 + k] * W[k*64 + f];
        x[(base + nn)*256 + t] = acc;
    }
}

// One wave (64 lanes) per edge; 4 edges per 256-thread block.
__global__ __launch_bounds__(256) void edge_msg_k(const float4* __restrict__ geom,
                                                  const int* __restrict__ dst,
                                                  const int* __restrict__ src,
                                                  const float* __restrict__ Wb,   // 32x64, round-offset
                                                  const float* __restrict__ bb,   // 64
                                                  const float* __restrict__ pw,   // 5x64
                                                  const float* __restrict__ x_old,
                                                  float* __restrict__ x_new) {
    __shared__ float Wl[KK*FF]; // 8 KB
    int t = threadIdx.x;
    #pragma unroll
    for (int i = t; i < KK*FF; i += 256) Wl[i] = Wb[i];
    __syncthreads();

    int e = blockIdx.x * 4 + (t >> 6);
    int f = t & 63;

    float4 g4 = geom[e];
    float d = g4.x, rh0 = g4.y, rh1 = g4.z, rh2 = g4.w;

    // rbf: lane (f&31) computes its own basis value, broadcast via shfl
    const float wdt = 2.5f / 31.0f;
    const float inv_w = 31.0f / 2.5f;
    int k = f & 31;
    float tt = (d - wdt * (float)k) * inv_w;
    float my_rbf = __expf(-tt * tt);

    float G = 0.0f;
    #pragma unroll
    for (int kk = 0; kk < KK; ++kk) {
        float rb = __shfl(my_rbf, kk, 64);
        G += rb * Wl[kk*64 + f];
    }

    int si = src[e], di = dst[e];
    const float* a = x_old + (size_t)si * 256;
    float a0  = a[f];
    float av0 = a[64 + f];
    float av1 = a[128 + f];
    float av2 = a[192 + f];

    float b_f = bb[f];
    float p0 = pw[f], p1 = pw[64+f], p2 = pw[128+f], p3 = pw[192+f], p4 = pw[256+f];

    float g0 = G + b_f;
    float dotav = av0*rh0 + av1*rh1 + av2*rh2;
    float m0 = p0*a0*g0 + p1*dotav*G;
    float tA = p2*a0*G;   // scales rhat
    float tB = p3*g0;     // scales av
    float tC = p4*G;      // scales cross(av, rhat-part)
    float m1 = tA*rh0 + tB*av0 + tC*(av1*rh2 - av2*rh1);
    float m2 = tA*rh1 + tB*av1 + tC*(av2*rh0 - av0*rh2);
    float m3 = tA*rh2 + tB*av2 + tC*(av0*rh1 - av1*rh0);

    float* o = x_new + (size_t)di * 256;
    atomicAdd(o + f,        m0);
    atomicAdd(o + 64  + f,  m1);
    atomicAdd(o + 128 + f,  m2);
    atomicAdd(o + 192 + f,  m3);
}

__global__ __launch_bounds__(256) void node_out_k(const float* __restrict__ x,
                                                  const float* __restrict__ W0,
                                                  const float* __restrict__ W1,
                                                  const float* __restrict__ bout,
                                                  float* __restrict__ out) {
    int n = blockIdx.x * 4 + (threadIdx.x >> 6);
    int f = threadIdx.x & 63;
    float w0 = W0[f], w1 = W1[f];
    const float* xp = x + (size_t)n * 256;
    float s0 = xp[f]       * w0;
    float s1 = xp[64  + f] * w1;
    float s2 = xp[128 + f] * w1;
    float s3 = xp[192 + f] * w1;
    #pragma unroll
    for (int off = 32; off >= 1; off >>= 1) {
        s0 += __shfl_down(s0, off, 64);
        s1 += __shfl_down(s1, off, 64);
        s2 += __shfl_down(s2, off, 64);
        s3 += __shfl_down(s3, off, 64);
    }
    if (f == 0) {
        float b = bout[0];
        out[n*4 + 0] = s0 + b;
        out[n*4 + 1] = s1;
        out[n*4 + 2] = s2;
        out[n*4 + 3] = s3;
    }
}

extern "C" void kernel_launch(void* const* d_in, const int* in_sizes, int n_in,
                              void* d_out, int out_size, void* d_ws, size_t ws_size,
                              hipStream_t stream) {
    const float* x_dftb  = (const float*)d_in[0];
    const float* coords  = (const float*)d_in[1];
    const int*   dst     = (const int*)  d_in[2];
    const int*   src     = (const int*)  d_in[3];
    const float* W_in0   = (const float*)d_in[4];
    const float* W_in1   = (const float*)d_in[5];
    const float* b_in    = (const float*)d_in[6];
    const float* W_basis = (const float*)d_in[7];
    const float* b_basis = (const float*)d_in[8];
    const float* path_w  = (const float*)d_in[9];
    const float* W_out0  = (const float*)d_in[10];
    const float* W_out1  = (const float*)d_in[11];
    const float* b_out   = (const float*)d_in[12];
    float* out = (float*)d_out;

    float* xA = (float*)d_ws;
    float* xB = xA + (size_t)N_NODES * 256;
    float4* geom = (float4*)(xB + (size_t)N_NODES * 256);

    edge_geom_k<<<(N_EDGES + 255)/256, 256, 0, stream>>>(coords, dst, src, geom);
    node_in_k<<<N_NODES / NPB, 256, 0, stream>>>(x_dftb, W_in0, W_in1, b_in, xA);

    float* xo = xA;
    float* xn = xB;
    for (int i = 0; i < 3; ++i) {
        hipMemcpyAsync(xn, xo, (size_t)N_NODES * 256 * sizeof(float),
                       hipMemcpyDeviceToDevice, stream);
        edge_msg_k<<<N_EDGES / 4, 256, 0, stream>>>(geom, dst, src,
                                                    W_basis + i*KK*FF,
                                                    b_basis + i*FF,
                                                    path_w + i*5*FF,
                                                    xo, xn);
        float* tmp = xo; xo = xn; xn = tmp;
    }
    node_out_k<<<N_NODES / 4, 256, 0, stream>>>(xo, W_out0, W_out1, b_out, out);
}

// Round 2
// 490.729 us; speedup vs baseline: 1.7375x; 1.7375x over previous
//
#include <hip/hip_runtime.h>

#define N_NODES 20000
#define N_EDGES 320000
#define FF 64
#define KK 32

// ws layout (bytes, in order):
//   xA    : N_NODES*256*4 = 20,480,000
//   xB    : 20,480,000
//   egeom : N_EDGES*16    =  5,120,000   (d, rhx, rhy, rhz) in dst-sorted order
//   esrc  : N_EDGES*4     =  1,280,000   (src idx, dst-sorted order)
//   rowptr: (N_NODES+1)*4 =     80,004
//   cnt   : N_NODES*4
//   fill  : N_NODES*4
// total ~47.6 MB

__global__ __launch_bounds__(256) void hist_k(const int* __restrict__ dst,
                                              int* __restrict__ cnt) {
    int e = blockIdx.x * 256 + threadIdx.x;
    if (e >= N_EDGES) return;
    atomicAdd(&cnt[dst[e]], 1);
}

__global__ __launch_bounds__(1024) void scan_k(const int* __restrict__ cnt,
                                               int* __restrict__ rowptr) {
    __shared__ int part[1024];
    int t = threadIdx.x;
    const int CH = 20;                 // 1024*20 >= 20000
    int lo = t * CH;
    int hi = lo + CH; if (hi > N_NODES) hi = N_NODES;
    int s = 0;
    for (int i = lo; i < hi && lo < N_NODES; ++i) s += cnt[i];
    if (lo >= N_NODES) s = 0;
    part[t] = s;
    __syncthreads();
    for (int off = 1; off < 1024; off <<= 1) {
        int tmp = (t >= off) ? part[t - off] : 0;
        __syncthreads();
        part[t] += tmp;
        __syncthreads();
    }
    int excl = part[t] - s;
    if (lo < N_NODES) {
        int run = excl;
        for (int i = lo; i < hi; ++i) { rowptr[i] = run; run += cnt[i]; }
    }
    if (t == 1023) rowptr[N_NODES] = part[1023];
}

__global__ __launch_bounds__(256) void scatter_k(const float* __restrict__ coords,
                                                 const int* __restrict__ dst,
                                                 const int* __restrict__ src,
                                                 const int* __restrict__ rowptr,
                                                 int* __restrict__ fill,
                                                 int* __restrict__ esrc,
                                                 float4* __restrict__ egeom) {
    int e = blockIdx.x * 256 + threadIdx.x;
    if (e >= N_EDGES) return;
    int di = dst[e], si = src[e];
    int pos = rowptr[di] + atomicAdd(&fill[di], 1);
    float rx = coords[di*3+0] - coords[si*3+0];
    float ry = coords[di*3+1] - coords[si*3+1];
    float rz = coords[di*3+2] - coords[si*3+2];
    float d = sqrtf(rx*rx + ry*ry + rz*rz + 1e-12f);
    float inv = 1.0f / d;
    esrc[pos] = si;
    egeom[pos] = make_float4(d, rx*inv, ry*inv, rz*inv);
}

#define NPB 8
__global__ __launch_bounds__(256) void node_in_k(const float* __restrict__ x_dftb,
                                                 const float* __restrict__ W0,
                                                 const float* __restrict__ W1,
                                                 const float* __restrict__ bin,
                                                 float* __restrict__ x) {
    __shared__ float Wl[2*64*64];   // 32 KB
    __shared__ float xin[NPB*256];  // 8 KB
    int t = threadIdx.x;
    #pragma unroll
    for (int i = t; i < 8192; i += 256) Wl[i] = (i < 4096) ? W0[i] : W1[i-4096];
    int base = blockIdx.x * NPB;
    #pragma unroll
    for (int i = t; i < NPB*256; i += 256) xin[i] = x_dftb[base*256 + i];
    __syncthreads();
    int l = t >> 6, f = t & 63;
    const float* W = (l == 0) ? Wl : (Wl + 4096);
    float bb = (l == 0) ? bin[f] : 0.0f;
    for (int nn = 0; nn < NPB; ++nn) {
        float acc = bb;
        #pragma unroll
        for (int k = 0; k < 64; ++k) acc += xin[nn*256 + l*64 + k] * W[k*64 + f];
        x[(base + nn)*256 + t] = acc;
    }
}

// One wave (64 lanes = 64 features) per dst node; 4 nodes per block.
// No atomics: each wave owns its node's output row.
__global__ __launch_bounds__(256) void msg_k(const int* __restrict__ rowptr,
                                             const int* __restrict__ esrc,
                                             const float4* __restrict__ egeom,
                                             const float* __restrict__ Wb,   // 32x64 (round)
                                             const float* __restrict__ bbv,  // 64
                                             const float* __restrict__ pw,   // 5x64
                                             const float* __restrict__ x_old,
                                             float* __restrict__ x_new) {
    int t = threadIdx.x;
    int n = blockIdx.x * 4 + (t >> 6);
    int f = t & 63;

    // W_basis column f in registers (statically indexed under full unroll)
    float wreg[KK];
    #pragma unroll
    for (int k = 0; k < KK; ++k) wreg[k] = Wb[k*64 + f];

    const float* xo = x_old + (size_t)n * 256;
    float acc0 = xo[f], acc1 = xo[64+f], acc2 = xo[128+f], acc3 = xo[192+f];

    float b_f = bbv[f];
    float p0 = pw[f], p1 = pw[64+f], p2 = pw[128+f], p3 = pw[192+f], p4 = pw[256+f];

    const float wdt   = 2.5f / 31.0f;
    const float inv_w = 31.0f / 2.5f;
    float ck = wdt * (float)(f & 31);

    int beg = rowptr[n], end = rowptr[n+1];
    for (int e = beg; e < end; ++e) {
        int si = esrc[e];
        float4 g4 = egeom[e];
        float tt = (g4.x - ck) * inv_w;
        float my_rbf = __expf(-tt * tt);
        float G = 0.0f;
        #pragma unroll
        for (int k = 0; k < KK; ++k) G += __shfl(my_rbf, k, 64) * wreg[k];

        const float* a = x_old + (size_t)si * 256;
        float a0  = a[f];
        float av0 = a[64+f], av1 = a[128+f], av2 = a[192+f];

        float g0 = G + b_f;
        float dotav = av0*g4.y + av1*g4.z + av2*g4.w;
        acc0 += p0*a0*g0 + p1*dotav*G;
        float tA = p2*a0*G, tB = p3*g0, tC = p4*G;
        acc1 += tA*g4.y + tB*av0 + tC*(av1*g4.w - av2*g4.z);
        acc2 += tA*g4.z + tB*av1 + tC*(av2*g4.y - av0*g4.w);
        acc3 += tA*g4.w + tB*av2 + tC*(av0*g4.z - av1*g4.y);
    }

    float* o = x_new + (size_t)n * 256;
    o[f] = acc0; o[64+f] = acc1; o[128+f] = acc2; o[192+f] = acc3;
}

__global__ __launch_bounds__(256) void node_out_k(const float* __restrict__ x,
                                                  const float* __restrict__ W0,
                                                  const float* __restrict__ W1,
                                                  const float* __restrict__ bout,
                                                  float* __restrict__ out) {
    int n = blockIdx.x * 4 + (threadIdx.x >> 6);
    int f = threadIdx.x & 63;
    float w0 = W0[f], w1 = W1[f];
    const float* xp = x + (size_t)n * 256;
    float s0 = xp[f]       * w0;
    float s1 = xp[64  + f] * w1;
    float s2 = xp[128 + f] * w1;
    float s3 = xp[192 + f] * w1;
    #pragma unroll
    for (int off = 32; off >= 1; off >>= 1) {
        s0 += __shfl_down(s0, off, 64);
        s1 += __shfl_down(s1, off, 64);
        s2 += __shfl_down(s2, off, 64);
        s3 += __shfl_down(s3, off, 64);
    }
    if (f == 0) {
        float b = bout[0];
        out[n*4 + 0] = s0 + b;
        out[n*4 + 1] = s1;
        out[n*4 + 2] = s2;
        out[n*4 + 3] = s3;
    }
}

extern "C" void kernel_launch(void* const* d_in, const int* in_sizes, int n_in,
                              void* d_out, int out_size, void* d_ws, size_t ws_size,
                              hipStream_t stream) {
    const float* x_dftb  = (const float*)d_in[0];
    const float* coords  = (const float*)d_in[1];
    const int*   dst     = (const int*)  d_in[2];
    const int*   src     = (const int*)  d_in[3];
    const float* W_in0   = (const float*)d_in[4];
    const float* W_in1   = (const float*)d_in[5];
    const float* b_in    = (const float*)d_in[6];
    const float* W_basis = (const float*)d_in[7];
    const float* b_basis = (const float*)d_in[8];
    const float* path_w  = (const float*)d_in[9];
    const float* W_out0  = (const float*)d_in[10];
    const float* W_out1  = (const float*)d_in[11];
    const float* b_out   = (const float*)d_in[12];
    float* out = (float*)d_out;

    char* p = (char*)d_ws;
    float*  xA     = (float*)p;                 p += (size_t)N_NODES*256*4;
    float*  xB     = (float*)p;                 p += (size_t)N_NODES*256*4;
    float4* egeom  = (float4*)p;                p += (size_t)N_EDGES*16;
    int*    esrc   = (int*)p;                   p += (size_t)N_EDGES*4;
    int*    rowptr = (int*)p;                   p += (size_t)(N_NODES+1)*4;
    int*    cnt    = (int*)p;                   p += (size_t)N_NODES*4;
    int*    fill   = (int*)p;                   p += (size_t)N_NODES*4;

    hipMemsetAsync(cnt,  0, (size_t)N_NODES*4, stream);
    hipMemsetAsync(fill, 0, (size_t)N_NODES*4, stream);

    hist_k   <<<(N_EDGES+255)/256, 256, 0, stream>>>(dst, cnt);
    scan_k   <<<1, 1024, 0, stream>>>(cnt, rowptr);
    scatter_k<<<(N_EDGES+255)/256, 256, 0, stream>>>(coords, dst, src, rowptr, fill,
                                                     esrc, egeom);
    node_in_k<<<N_NODES/NPB, 256, 0, stream>>>(x_dftb, W_in0, W_in1, b_in, xA);

    float* xo = xA;
    float* xn = xB;
    for (int i = 0; i < 3; ++i) {
        msg_k<<<N_NODES/4, 256, 0, stream>>>(rowptr, esrc, egeom,
                                             W_basis + i*KK*FF,
                                             b_basis + i*FF,
                                             path_w  + i*5*FF,
                                             xo, xn);
        float* tmp = xo; xo = xn; xn = tmp;
    }
    node_out_k<<<N_NODES/4, 256, 0, stream>>>(xo, W_out0, W_out1, b_out, out);
}

// Round 3
// 484.602 us; speedup vs baseline: 1.7595x; 1.0126x over previous
//
#include <hip/hip_runtime.h>

#define N_NODES 20000
#define N_EDGES 320000
#define FF 64
#define KK 32

// x layout: [n][f][l] (l=0..3) -> lane f reads one float4 / ushort4 per row.
// ws layout (bytes):
//   xA f32 : 20,480,000
//   xB f32 : 20,480,000
//   bA bf16: 10,240,000   (optional, if ws fits)
//   bB bf16: 10,240,000
//   egeom  :  5,120,000
//   esrc   :  1,280,000
//   rowptr :     80,004
//   cnt    :     80,000
//   fill   :     80,000

__device__ __forceinline__ float bf2f(unsigned short h) {
    return __uint_as_float(((unsigned)h) << 16);
}
__device__ __forceinline__ unsigned short f2bf(float x) {
    unsigned u = __float_as_uint(x);
    unsigned r = (u + 0x7FFFu + ((u >> 16) & 1u)) >> 16;
    return (unsigned short)r;
}

__global__ __launch_bounds__(256) void hist_k(const int* __restrict__ dst,
                                              int* __restrict__ cnt) {
    int e = blockIdx.x * 256 + threadIdx.x;
    if (e >= N_EDGES) return;
    atomicAdd(&cnt[dst[e]], 1);
}

__global__ __launch_bounds__(1024) void scan_k(const int* __restrict__ cnt,
                                               int* __restrict__ rowptr) {
    __shared__ int part[1024];
    int t = threadIdx.x;
    const int CH = 20;
    int lo = t * CH;
    int hi = lo + CH; if (hi > N_NODES) hi = N_NODES;
    int s = 0;
    for (int i = lo; i < hi && lo < N_NODES; ++i) s += cnt[i];
    if (lo >= N_NODES) s = 0;
    part[t] = s;
    __syncthreads();
    for (int off = 1; off < 1024; off <<= 1) {
        int tmp = (t >= off) ? part[t - off] : 0;
        __syncthreads();
        part[t] += tmp;
        __syncthreads();
    }
    int excl = part[t] - s;
    if (lo < N_NODES) {
        int run = excl;
        for (int i = lo; i < hi; ++i) { rowptr[i] = run; run += cnt[i]; }
    }
    if (t == 1023) rowptr[N_NODES] = part[1023];
}

__global__ __launch_bounds__(256) void scatter_k(const float* __restrict__ coords,
                                                 const int* __restrict__ dst,
                                                 const int* __restrict__ src,
                                                 const int* __restrict__ rowptr,
                                                 int* __restrict__ fill,
                                                 int* __restrict__ esrc,
                                                 float4* __restrict__ egeom) {
    int e = blockIdx.x * 256 + threadIdx.x;
    if (e >= N_EDGES) return;
    int di = dst[e], si = src[e];
    int pos = rowptr[di] + atomicAdd(&fill[di], 1);
    float rx = coords[di*3+0] - coords[si*3+0];
    float ry = coords[di*3+1] - coords[si*3+1];
    float rz = coords[di*3+2] - coords[si*3+2];
    float d = sqrtf(rx*rx + ry*ry + rz*rz + 1e-12f);
    float inv = 1.0f / d;
    esrc[pos] = si;
    egeom[pos] = make_float4(d, rx*inv, ry*inv, rz*inv);
}

// Block = 4 nodes (wave per node); thread (q=t>>6 -> node, f=t&63).
// Each thread computes all 4 l-components of feature f, writes float4 (+bf16).
__global__ __launch_bounds__(256) void node_in_k(const float* __restrict__ x_dftb,
                                                 const float* __restrict__ W0,
                                                 const float* __restrict__ W1,
                                                 const float* __restrict__ bin,
                                                 float* __restrict__ x,
                                                 ushort4* __restrict__ xb) {
    __shared__ float Wl[2*64*64];   // 32 KB
    __shared__ float xin[4*256];    // 4 nodes input, [node][l][k] layout
    int t = threadIdx.x;
    for (int i = t; i < 8192; i += 256) Wl[i] = (i < 4096) ? W0[i] : W1[i-4096];
    int base = blockIdx.x * 4;
    for (int i = t; i < 4*256; i += 256) xin[i] = x_dftb[base*256 + i];
    __syncthreads();
    int q = t >> 6, f = t & 63;
    int n = base + q;
    const float* xi = xin + q*256;
    float a0 = bin[f], a1 = 0.f, a2 = 0.f, a3 = 0.f;
    #pragma unroll
    for (int k = 0; k < 64; ++k) {
        float w0 = Wl[k*64 + f];
        float w1 = Wl[4096 + k*64 + f];
        a0 += xi[k]       * w0;
        a1 += xi[64 + k]  * w1;
        a2 += xi[128 + k] * w1;
        a3 += xi[192 + k] * w1;
    }
    *(float4*)(x + (size_t)n*256 + f*4) = make_float4(a0, a1, a2, a3);
    if (xb) {
        ushort4 h; h.x = f2bf(a0); h.y = f2bf(a1); h.z = f2bf(a2); h.w = f2bf(a3);
        xb[(size_t)n*64 + f] = h;
    }
}

// One wave per dst node, lane = feature. 4-edge batched gathers.
template<int GB>
__global__ __launch_bounds__(256) void msg_k(const int* __restrict__ rowptr,
                                             const int* __restrict__ esrc,
                                             const float4* __restrict__ egeom,
                                             const float* __restrict__ Wb,
                                             const float* __restrict__ bbv,
                                             const float* __restrict__ pw,
                                             const float* __restrict__ xo_f,
                                             const ushort4* __restrict__ xo_b,
                                             float* __restrict__ xn_f,
                                             ushort4* __restrict__ xn_b) {
    int t = threadIdx.x;
    int n = blockIdx.x * 4 + (t >> 6);
    int f = t & 63;

    float wreg[KK];
    #pragma unroll
    for (int k = 0; k < KK; ++k) wreg[k] = Wb[k*64 + f];

    float4 self = *(const float4*)(xo_f + (size_t)n*256 + f*4);
    float acc0 = self.x, acc1 = self.y, acc2 = self.z, acc3 = self.w;

    float b_f = bbv[f];
    float p0 = pw[f], p1 = pw[64+f], p2 = pw[128+f], p3 = pw[192+f], p4 = pw[256+f];
    const float wdt = 2.5f / 31.0f, inv_w = 31.0f / 2.5f;
    float ck = wdt * (float)(f & 31);

    int beg = rowptr[n], end = rowptr[n+1];
    int e = beg;
    for (; e + 4 <= end; e += 4) {
        int si[4];
        float4 gg[4];
        #pragma unroll
        for (int j = 0; j < 4; ++j) { si[j] = esrc[e+j]; gg[j] = egeom[e+j]; }

        float A[4][4];
        if (GB) {
            #pragma unroll
            for (int j = 0; j < 4; ++j) {
                ushort4 h = xo_b[(size_t)si[j]*64 + f];
                A[j][0] = bf2f(h.x); A[j][1] = bf2f(h.y);
                A[j][2] = bf2f(h.z); A[j][3] = bf2f(h.w);
            }
        } else {
            #pragma unroll
            for (int j = 0; j < 4; ++j) {
                float4 v = *(const float4*)(xo_f + (size_t)si[j]*256 + f*4);
                A[j][0] = v.x; A[j][1] = v.y; A[j][2] = v.z; A[j][3] = v.w;
            }
        }

        float rb[4];
        #pragma unroll
        for (int j = 0; j < 4; ++j) {
            float tt = (gg[j].x - ck) * inv_w;
            rb[j] = __expf(-tt * tt);
        }
        float G[4] = {0.f, 0.f, 0.f, 0.f};
        #pragma unroll
        for (int k = 0; k < KK; ++k) {
            float w = wreg[k];
            #pragma unroll
            for (int j = 0; j < 4; ++j) G[j] += __shfl(rb[j], k, 64) * w;
        }

        #pragma unroll
        for (int j = 0; j < 4; ++j) {
            float g0v = G[j] + b_f;
            float dotav = A[j][1]*gg[j].y + A[j][2]*gg[j].z + A[j][3]*gg[j].w;
            acc0 += p0*A[j][0]*g0v + p1*dotav*G[j];
            float tA = p2*A[j][0]*G[j], tB = p3*g0v, tC = p4*G[j];
            acc1 += tA*gg[j].y + tB*A[j][1] + tC*(A[j][2]*gg[j].w - A[j][3]*gg[j].z);
            acc2 += tA*gg[j].z + tB*A[j][2] + tC*(A[j][3]*gg[j].y - A[j][1]*gg[j].w);
            acc3 += tA*gg[j].w + tB*A[j][3] + tC*(A[j][1]*gg[j].z - A[j][2]*gg[j].y);
        }
    }
    for (; e < end; ++e) {
        int sj = esrc[e];
        float4 g4 = egeom[e];
        float a0, av0, av1, av2;
        if (GB) {
            ushort4 h = xo_b[(size_t)sj*64 + f];
            a0 = bf2f(h.x); av0 = bf2f(h.y); av1 = bf2f(h.z); av2 = bf2f(h.w);
        } else {
            float4 v = *(const float4*)(xo_f + (size_t)sj*256 + f*4);
            a0 = v.x; av0 = v.y; av1 = v.z; av2 = v.w;
        }
        float tt = (g4.x - ck) * inv_w;
        float my_rbf = __expf(-tt * tt);
        float Gs = 0.f;
        #pragma unroll
        for (int k = 0; k < KK; ++k) Gs += __shfl(my_rbf, k, 64) * wreg[k];
        float g0v = Gs + b_f;
        float dotav = av0*g4.y + av1*g4.z + av2*g4.w;
        acc0 += p0*a0*g0v + p1*dotav*Gs;
        float tA = p2*a0*Gs, tB = p3*g0v, tC = p4*Gs;
        acc1 += tA*g4.y + tB*av0 + tC*(av1*g4.w - av2*g4.z);
        acc2 += tA*g4.z + tB*av1 + tC*(av2*g4.y - av0*g4.w);
        acc3 += tA*g4.w + tB*av2 + tC*(av0*g4.z - av1*g4.y);
    }

    *(float4*)(xn_f + (size_t)n*256 + f*4) = make_float4(acc0, acc1, acc2, acc3);
    if (GB) {
        ushort4 h; h.x = f2bf(acc0); h.y = f2bf(acc1); h.z = f2bf(acc2); h.w = f2bf(acc3);
        xn_b[(size_t)n*64 + f] = h;
    }
}

__global__ __launch_bounds__(256) void node_out_k(const float* __restrict__ x,
                                                  const float* __restrict__ W0,
                                                  const float* __restrict__ W1,
                                                  const float* __restrict__ bout,
                                                  float* __restrict__ out) {
    int n = blockIdx.x * 4 + (threadIdx.x >> 6);
    int f = threadIdx.x & 63;
    float w0 = W0[f], w1 = W1[f];
    float4 v = *(const float4*)(x + (size_t)n*256 + f*4);
    float s0 = v.x * w0, s1 = v.y * w1, s2 = v.z * w1, s3 = v.w * w1;
    #pragma unroll
    for (int off = 32; off >= 1; off >>= 1) {
        s0 += __shfl_down(s0, off, 64);
        s1 += __shfl_down(s1, off, 64);
        s2 += __shfl_down(s2, off, 64);
        s3 += __shfl_down(s3, off, 64);
    }
    if (f == 0) {
        float b = bout[0];
        out[n*4 + 0] = s0 + b;
        out[n*4 + 1] = s1;
        out[n*4 + 2] = s2;
        out[n*4 + 3] = s3;
    }
}

extern "C" void kernel_launch(void* const* d_in, const int* in_sizes, int n_in,
                              void* d_out, int out_size, void* d_ws, size_t ws_size,
                              hipStream_t stream) {
    const float* x_dftb  = (const float*)d_in[0];
    const float* coords  = (const float*)d_in[1];
    const int*   dst     = (const int*)  d_in[2];
    const int*   src     = (const int*)  d_in[3];
    const float* W_in0   = (const float*)d_in[4];
    const float* W_in1   = (const float*)d_in[5];
    const float* b_in    = (const float*)d_in[6];
    const float* W_basis = (const float*)d_in[7];
    const float* b_basis = (const float*)d_in[8];
    const float* path_w  = (const float*)d_in[9];
    const float* W_out0  = (const float*)d_in[10];
    const float* W_out1  = (const float*)d_in[11];
    const float* b_out   = (const float*)d_in[12];
    float* out = (float*)d_out;

    const size_t XF = (size_t)N_NODES * 256 * 4;   // f32 x buffer bytes
    const size_t XB = (size_t)N_NODES * 64 * 8;    // bf16 x buffer bytes
    const size_t EG = (size_t)N_EDGES * 16;
    const size_t ES = (size_t)N_EDGES * 4;
    const size_t need_bf16 = 2*XF + 2*XB + EG + ES + (size_t)(N_NODES+1)*4
                           + (size_t)N_NODES*4*2;
    int use_bf16 = (ws_size >= need_bf16) ? 1 : 0;

    char* p = (char*)d_ws;
    float*   xA = (float*)p;    p += XF;
    float*   xB = (float*)p;    p += XF;
    ushort4* bA = nullptr;
    ushort4* bB = nullptr;
    if (use_bf16) { bA = (ushort4*)p; p += XB; bB = (ushort4*)p; p += XB; }
    float4* egeom  = (float4*)p;  p += EG;
    int*    esrc   = (int*)p;     p += ES;
    int*    rowptr = (int*)p;     p += (size_t)(N_NODES+1)*4;
    int*    cnt    = (int*)p;     p += (size_t)N_NODES*4;
    int*    fill   = (int*)p;     p += (size_t)N_NODES*4;

    hipMemsetAsync(cnt,  0, (size_t)N_NODES*4, stream);
    hipMemsetAsync(fill, 0, (size_t)N_NODES*4, stream);

    hist_k   <<<(N_EDGES+255)/256, 256, 0, stream>>>(dst, cnt);
    scan_k   <<<1, 1024, 0, stream>>>(cnt, rowptr);
    scatter_k<<<(N_EDGES+255)/256, 256, 0, stream>>>(coords, dst, src, rowptr, fill,
                                                     esrc, egeom);
    node_in_k<<<N_NODES/4, 256, 0, stream>>>(x_dftb, W_in0, W_in1, b_in, xA, bA);

    float*   xo = xA; float*   xn = xB;
    ushort4* bo = bA; ushort4* bn = bB;
    for (int i = 0; i < 3; ++i) {
        if (use_bf16)
            msg_k<1><<<N_NODES/4, 256, 0, stream>>>(rowptr, esrc, egeom,
                                                    W_basis + i*KK*FF, b_basis + i*FF,
                                                    path_w + i*5*FF, xo, bo, xn, bn);
        else
            msg_k<0><<<N_NODES/4, 256, 0, stream>>>(rowptr, esrc, egeom,
                                                    W_basis + i*KK*FF, b_basis + i*FF,
                                                    path_w + i*5*FF, xo, nullptr, xn, nullptr);
        float* tf = xo; xo = xn; xn = tf;
        ushort4* tb = bo; bo = bn; bn = tb;
    }
    node_out_k<<<N_NODES/4, 256, 0, stream>>>(xo, W_out0, W_out1, b_out, out);
}